// Round 9
// baseline (392.079 us; speedup 1.0000x reference)
//
#include <hip/hip_runtime.h>

#define N_NODES 50000
#define N_EDGES 800000
#define D_FEAT 32
#define NUM_GRAPHS 64
#define FEATS 320
#define NBIN 128                         // bins of 512 nodes (98 used)
#define BINSH 9
#define CE 4096                          // edges per binning chunk
#define NCHUNK ((N_EDGES + CE - 1) / CE) // 196
#define NPB ((N_NODES + 511) / 512)      // 98 place blocks
#define XROW4 (N_NODES * 8)              // ushort4 per x copy (N*32 bf16)
#define XF4   (N_NODES * 4)              // float4 per x copy (3.2 MB / 16B)

// bf16 helpers (RNE pack, shift unpack) — values finite, no NaN path needed
__device__ __forceinline__ unsigned short f2bf(float f) {
    unsigned int u = __float_as_uint(f);
    u = (u + 0x7fffu + ((u >> 16) & 1u)) >> 16;
    return (unsigned short)u;
}
__device__ __forceinline__ float bf2f(unsigned short h) {
    return __uint_as_float((unsigned int)h << 16);
}

// ---------------- atomic-free binning sort (counts -> positions -> place) ----

__global__ void binA_kernel(const int* __restrict__ dst, int* __restrict__ counts, int n) {
    __shared__ int h[NBIN];
    int t = threadIdx.x;
    if (t < NBIN) h[t] = 0;
    __syncthreads();
    int s0 = blockIdx.x * CE, e0 = min(s0 + CE, n);
    for (int i = s0 + t; i < e0; i += blockDim.x)
        atomicAdd(&h[dst[i] >> BINSH], 1);
    __syncthreads();
    if (t < NBIN) counts[blockIdx.x * NBIN + t] = h[t];
}

__global__ void binB_kernel(int* __restrict__ counts, int* __restrict__ binBase) {
    __shared__ int s[NBIN];
    int b = threadIdx.x;
    int tot = 0;
    #pragma unroll 8
    for (int c = 0; c < NCHUNK; ++c) tot += counts[c * NBIN + b];
    s[b] = tot;
    __syncthreads();
    for (int off = 1; off < NBIN; off <<= 1) {
        int u = (b >= off) ? s[b - off] : 0;
        __syncthreads();
        s[b] += u;
        __syncthreads();
    }
    int base = s[b] - tot;   // exclusive
    binBase[b] = base;
    if (b == NBIN - 1) binBase[NBIN] = s[b];
    int running = base;
    #pragma unroll 4
    for (int c = 0; c < NCHUNK; ++c) {
        int idx = c * NBIN + b;
        int v = counts[idx];
        counts[idx] = running;
        running += v;
    }
}

__global__ __launch_bounds__(256) void binC_kernel(const int* __restrict__ src,
                                                   const int* __restrict__ dst,
                                                   const float* __restrict__ w,
                                                   const int* __restrict__ counts,
                                                   int2* __restrict__ tmp, int n) {
    __shared__ int h[NBIN], sc[NBIN], cur[NBIN], gbase[NBIN];
    __shared__ int2 srec[CE];
    __shared__ unsigned char sbin[CE];
    int t = threadIdx.x;
    if (t < NBIN) h[t] = 0;
    __syncthreads();
    int s0 = blockIdx.x * CE, e0 = min(s0 + CE, n);
    int cnt = e0 - s0;
    for (int i = s0 + t; i < e0; i += blockDim.x)
        atomicAdd(&h[dst[i] >> BINSH], 1);
    __syncthreads();
    if (t < NBIN) sc[t] = h[t];
    __syncthreads();
    for (int off = 1; off < NBIN; off <<= 1) {
        int u = (t < NBIN && t >= off) ? sc[t - off] : 0;
        __syncthreads();
        if (t < NBIN) sc[t] += u;   // inclusive; exclusive = sc[b]-h[b]
        __syncthreads();
    }
    if (t < NBIN) {
        cur[t] = 0;
        gbase[t] = counts[blockIdx.x * NBIN + t];
    }
    __syncthreads();
    for (int i = s0 + t; i < e0; i += blockDim.x) {
        int d = dst[i];
        int b = d >> BINSH;
        int pos = (sc[b] - h[b]) + atomicAdd(&cur[b], 1);   // LDS atomic: cheap
        srec[pos] = make_int2(src[i] | ((int)f2bf(w[i]) << 16), d & 511);
        sbin[pos] = (unsigned char)b;
    }
    __syncthreads();
    for (int j = t; j < cnt; j += blockDim.x) {
        int b = sbin[j];
        tmp[gbase[b] + (j - (sc[b] - h[b]))] = srec[j];   // coalesced runs per bin
    }
}

__global__ __launch_bounds__(256) void place_kernel(const int* __restrict__ binBase,
                                                    const int2* __restrict__ tmp,
                                                    unsigned int* __restrict__ edges,
                                                    int* __restrict__ rowptr, int n) {
    __shared__ int h[512], sc[512], cur[512];
    int b = blockIdx.x;
    int t = threadIdx.x;
    int base = binBase[b], end = binBase[b + 1];
    for (int i = t; i < 512; i += 256) { h[i] = 0; cur[i] = 0; }
    __syncthreads();
    for (int e = base + t; e < end; e += 256)
        atomicAdd(&h[tmp[e].y], 1);
    __syncthreads();
    for (int i = t; i < 512; i += 256) sc[i] = h[i];
    __syncthreads();
    for (int off = 1; off < 512; off <<= 1) {
        int i0 = t, i1 = t + 256;
        int a0 = (i0 >= off) ? sc[i0 - off] : 0;
        int a1 = (i1 >= off) ? sc[i1 - off] : 0;
        __syncthreads();
        sc[i0] += a0;
        sc[i1] += a1;
        __syncthreads();
    }
    int node0 = b << BINSH;
    for (int i = t; i < 512; i += 256) {
        int node = node0 + i;
        if (node <= n) rowptr[node] = base + sc[i] - h[i];   // exclusive
    }
    if (b == 0 && t == 0) rowptr[0] = 0;
    __syncthreads();
    for (int e = base + t; e < end; e += 256) {
        int2 p = tmp[e];
        int loc = p.y;
        int pos = base + (sc[loc] - h[loc]) + atomicAdd(&cur[loc], 1);
        edges[pos] = (unsigned int)p.x;
    }
}

// ---------------- X -> bf16 conversion ----------------

__global__ void cvt_kernel(const float4* __restrict__ xin, ushort4* __restrict__ xout, int n4) {
    int i = blockIdx.x * blockDim.x + threadIdx.x;
    if (i < n4) {
        float4 v = xin[i];
        ushort4 o;
        o.x = f2bf(v.x); o.y = f2bf(v.y); o.z = f2bf(v.z); o.w = f2bf(v.w);
        xout[i] = o;
    }
}

// ---------------- graph boundaries (batch is sorted) ----------------

__global__ void gbound_kernel(const int* __restrict__ batch, int* __restrict__ gstart, int n) {
    int i = blockIdx.x * blockDim.x + threadIdx.x;
    if (i >= n) return;
    int g = batch[i];
    int gp = (i == 0) ? -1 : batch[i - 1];
    for (int gg = gp + 1; gg <= g; ++gg) gstart[gg] = i;
    if (i == n - 1)
        for (int gg = g + 1; gg <= NUM_GRAPHS; ++gg) gstart[gg] = n;
}

// ---------------- pull-based X replication ----------------
// Blocks of class c = blockIdx&7 stream the canonical 3.2 MB x into xrep[c].
// The write lands in the replicating block's XCD L2; spmm blocks of the same
// blockIdx%8 class land on the same XCD (consistent round-robin dispatch) and
// gather from THEIR copy -> local-L2 hits instead of cross-fabric random 64B
// fetches. Correct regardless of the mapping (all copies identical).

__global__ __launch_bounds__(256) void repl_kernel(const float4* __restrict__ srcbuf,
                                                   float4* __restrict__ xrep) {
    int c = blockIdx.x & 7;
    int blk = blockIdx.x >> 3;              // 0..127 within copy
    float4* dst = xrep + (size_t)c * XF4;
    for (int i = blk * 256 + threadIdx.x; i < XF4; i += 128 * 256)
        dst[i] = srcbuf[i];
}

// ---------------- SpMM (pull, no atomics), D=32 bf16, 4B edge recs ----------
// 8 lanes/node; lane owns cols 4l..4l+3 (ushort4). Reads this block's XCD-
// local x copy. fp32 accum, bf16 store.

__global__ __launch_bounds__(256) void spmm_kernel(const ushort4* __restrict__ xrep,
                                                   ushort4* __restrict__ yout,
                                                   const int* __restrict__ rowptr,
                                                   const unsigned int* __restrict__ edges,
                                                   int n) {
    const ushort4* __restrict__ xin = xrep + (size_t)(blockIdx.x & 7) * XROW4;
    int lane = threadIdx.x & 7;
    int node = (blockIdx.x * blockDim.x + threadIdx.x) >> 3;
    if (node >= n) return;
    int e0 = rowptr[node], e1 = rowptr[node + 1];
    float a0 = 0.f, a1 = 0.f, a2 = 0.f, a3 = 0.f;
    int e = e0;
    int e8 = e0 + ((e1 - e0) & ~7);
    for (; e < e8; e += 8) {
        unsigned int r[8];
        #pragma unroll
        for (int u = 0; u < 8; ++u) r[u] = edges[e + u];
        ushort4 v[8];
        #pragma unroll
        for (int u = 0; u < 8; ++u)
            v[u] = xin[(size_t)(r[u] & 0xffff) * 8 + lane];
        #pragma unroll
        for (int u = 0; u < 8; ++u) {
            float w = bf2f((unsigned short)(r[u] >> 16));
            a0 += bf2f(v[u].x) * w;
            a1 += bf2f(v[u].y) * w;
            a2 += bf2f(v[u].z) * w;
            a3 += bf2f(v[u].w) * w;
        }
    }
    for (; e < e1; ++e) {
        unsigned int r = edges[e];
        ushort4 v = xin[(size_t)(r & 0xffff) * 8 + lane];
        float w = bf2f((unsigned short)(r >> 16));
        a0 += bf2f(v.x) * w; a1 += bf2f(v.y) * w; a2 += bf2f(v.z) * w; a3 += bf2f(v.w) * w;
    }
    yout[(size_t)node * 8 + lane] = make_ushort4(f2bf(a0), f2bf(a1), f2bf(a2), f2bf(a3));
}

// ---------------- fused pooling: 10 terms, 64 graphs x 16 slices -------------

struct PoolArgs10 {
    const unsigned short* P[10];
    const unsigned short* Q[10];
};

__global__ __launch_bounds__(320) void pool_kernel(PoolArgs10 a, const int* __restrict__ gstart,
                                                   float* __restrict__ out) {
    int k = threadIdx.x >> 5;
    int f = threadIdx.x & 31;
    int g = blockIdx.x >> 4;
    int s = blockIdx.x & 15;
    int gs = gstart[g], ge = gstart[g + 1];
    int len = ge - gs;
    int i0 = gs + ((len * s) >> 4);
    int i1 = gs + ((len * (s + 1)) >> 4);
    const unsigned short* __restrict__ P = a.P[k];
    const unsigned short* __restrict__ Q = a.Q[k];
    float acc = 0.f;
    if (Q) {
        for (int i = i0; i < i1; ++i)
            acc += fabsf(bf2f(P[(size_t)i * 32 + f]) - bf2f(Q[(size_t)i * 32 + f]));
    } else {
        for (int i = i0; i < i1; ++i)
            acc += bf2f(P[(size_t)i * 32 + f]);
    }
    if (i1 > i0) atomicAdd(&out[g * FEATS + k * 32 + f], acc);
}

__global__ void divide_kernel(float* __restrict__ out, const int* __restrict__ gstart, int total) {
    int i = blockIdx.x * blockDim.x + threadIdx.x;
    if (i < total) {
        int g = i / FEATS;
        float c = (float)(gstart[g + 1] - gstart[g]);
        out[i] /= fmaxf(c, 1.0f);
    }
}

// ---------------- host launch ----------------

extern "C" void kernel_launch(void* const* d_in, const int* in_sizes, int n_in,
                              void* d_out, int out_size, void* d_ws, size_t ws_size,
                              hipStream_t stream) {
    const float* X     = (const float*)d_in[0];
    const int*   ei    = (const int*)d_in[1];
    const float* ew    = (const float*)d_in[2];
    const int*   batch = (const int*)d_in[3];
    float* out = (float*)d_out;

    const int N = N_NODES, E = N_EDGES;
    const int* src = ei;
    const int* dst = ei + E;

    char* base = (char*)d_ws;
    size_t off = 0;
    auto alloc = [&](size_t bytes) -> void* {
        void* p = base + off;
        off += (bytes + 255) & ~(size_t)255;
        return p;
    };
    // bf16 diffusion chain buffers y[k] = P^k X, k=0..12 (y[0] = bf16(X))
    unsigned short* y[13];
    for (int k = 0; k <= 12; ++k) y[k] = (unsigned short*)alloc((size_t)N * 32 * 2);

    unsigned short* xrep = (unsigned short*)alloc((size_t)8 * N * 32 * 2);  // 8 x 3.2 MB
    int*  rowptr  = (int*)alloc((size_t)(N + 4) * 4);
    int*  gstart  = (int*)alloc((NUM_GRAPHS + 1) * 4);
    int*  counts  = (int*)alloc((size_t)NCHUNK * NBIN * 4);
    int*  binBase = (int*)alloc((NBIN + 1) * 4);
    int2* tmp     = (int2*)alloc((size_t)E * 8);
    unsigned int* edges = (unsigned int*)alloc((size_t)E * 4);

    hipMemsetAsync(out, 0, (size_t)out_size * 4, stream);

    // atomic-free CSR build: counts -> positions -> grouped tmp -> edges+rowptr
    binA_kernel<<<NCHUNK, 256, 0, stream>>>(dst, counts, E);
    binB_kernel<<<1, NBIN, 0, stream>>>(counts, binBase);
    binC_kernel<<<NCHUNK, 256, 0, stream>>>(src, dst, ew, counts, tmp, E);
    place_kernel<<<NPB, 256, 0, stream>>>(binBase, tmp, edges, rowptr, N);

    // X -> bf16; graph boundaries
    cvt_kernel<<<(N * 32 / 4 + 255) / 256, 256, 0, stream>>>((const float4*)X, (ushort4*)y[0],
                                                             N * 32 / 4);
    gbound_kernel<<<(N + 255) / 256, 256, 0, stream>>>(batch, gstart, N);

    // ---- single D=32 bf16 diffusion chain with per-step pull-replication
    const int SPMM_GRID = (N * 8 + 255) / 256;  // 1563 blocks, 32 nodes/block
    for (int k = 1; k <= 12; ++k) {
        repl_kernel<<<8 * 128, 256, 0, stream>>>((const float4*)y[k - 1], (float4*)xrep);
        spmm_kernel<<<SPMM_GRID, 256, 0, stream>>>((const ushort4*)xrep, (ushort4*)y[k],
                                                   rowptr, edges, N);
    }

    // ---- fused pooling of all 10 feature column-blocks
    // F0 = y8 | F1: |y1-y2|, |y2-y4|, |y4-y8|
    // F2 (ref order): |y3-y2|, |y5-y3|, |y9-y5|, |y6-y4|, |y10-y6|, |y12-y8|
    {
        PoolArgs10 p{};
        const unsigned short* Ps[10] = {y[8], y[1], y[2], y[4], y[3], y[5], y[9], y[6], y[10], y[12]};
        const unsigned short* Qs[10] = {nullptr, y[2], y[4], y[8], y[2], y[3], y[5], y[4], y[6], y[8]};
        for (int k = 0; k < 10; ++k) { p.P[k] = Ps[k]; p.Q[k] = Qs[k]; }
        pool_kernel<<<NUM_GRAPHS * 16, 320, 0, stream>>>(p, gstart, out);
    }

    divide_kernel<<<(out_size + 255) / 256, 256, 0, stream>>>(out, gstart, out_size);
}

// Round 10
// 348.979 us; speedup vs baseline: 1.1235x; 1.1235x over previous
//
#include <hip/hip_runtime.h>

#define N_NODES 50000
#define N_EDGES 800000
#define D_FEAT 32
#define NUM_GRAPHS 64
#define FEATS 320
#define NBIN 128                         // bins of 512 nodes (98 used)
#define BINSH 9
#define CE 4096                          // edges per binning chunk
#define NCHUNK ((N_EDGES + CE - 1) / CE) // 196
#define NPB ((N_NODES + 511) / 512)      // 98 place blocks

// bf16 helpers (RNE pack, shift unpack) — values finite, no NaN path needed
__device__ __forceinline__ unsigned short f2bf(float f) {
    unsigned int u = __float_as_uint(f);
    u = (u + 0x7fffu + ((u >> 16) & 1u)) >> 16;
    return (unsigned short)u;
}
__device__ __forceinline__ float bf2f(unsigned short h) {
    return __uint_as_float((unsigned int)h << 16);
}

// ---------------- atomic-free binning sort (counts -> positions -> place) ----

__global__ void binA_kernel(const int* __restrict__ dst, int* __restrict__ counts, int n) {
    __shared__ int h[NBIN];
    int t = threadIdx.x;
    if (t < NBIN) h[t] = 0;
    __syncthreads();
    int s0 = blockIdx.x * CE, e0 = min(s0 + CE, n);
    for (int i = s0 + t; i < e0; i += blockDim.x)
        atomicAdd(&h[dst[i] >> BINSH], 1);
    __syncthreads();
    if (t < NBIN) counts[blockIdx.x * NBIN + t] = h[t];
}

__global__ void binB_kernel(int* __restrict__ counts, int* __restrict__ binBase) {
    __shared__ int s[NBIN];
    int b = threadIdx.x;
    int tot = 0;
    #pragma unroll 8
    for (int c = 0; c < NCHUNK; ++c) tot += counts[c * NBIN + b];
    s[b] = tot;
    __syncthreads();
    for (int off = 1; off < NBIN; off <<= 1) {
        int u = (b >= off) ? s[b - off] : 0;
        __syncthreads();
        s[b] += u;
        __syncthreads();
    }
    int base = s[b] - tot;   // exclusive
    binBase[b] = base;
    if (b == NBIN - 1) binBase[NBIN] = s[b];
    int running = base;
    #pragma unroll 4
    for (int c = 0; c < NCHUNK; ++c) {
        int idx = c * NBIN + b;
        int v = counts[idx];
        counts[idx] = running;
        running += v;
    }
}

__global__ __launch_bounds__(256) void binC_kernel(const int* __restrict__ src,
                                                   const int* __restrict__ dst,
                                                   const float* __restrict__ w,
                                                   const int* __restrict__ counts,
                                                   int2* __restrict__ tmp, int n) {
    __shared__ int h[NBIN], sc[NBIN], cur[NBIN], gbase[NBIN];
    __shared__ int2 srec[CE];
    __shared__ unsigned char sbin[CE];
    int t = threadIdx.x;
    if (t < NBIN) h[t] = 0;
    __syncthreads();
    int s0 = blockIdx.x * CE, e0 = min(s0 + CE, n);
    int cnt = e0 - s0;
    for (int i = s0 + t; i < e0; i += blockDim.x)
        atomicAdd(&h[dst[i] >> BINSH], 1);
    __syncthreads();
    if (t < NBIN) sc[t] = h[t];
    __syncthreads();
    for (int off = 1; off < NBIN; off <<= 1) {
        int u = (t < NBIN && t >= off) ? sc[t - off] : 0;
        __syncthreads();
        if (t < NBIN) sc[t] += u;   // inclusive; exclusive = sc[b]-h[b]
        __syncthreads();
    }
    if (t < NBIN) {
        cur[t] = 0;
        gbase[t] = counts[blockIdx.x * NBIN + t];
    }
    __syncthreads();
    for (int i = s0 + t; i < e0; i += blockDim.x) {
        int d = dst[i];
        int b = d >> BINSH;
        int pos = (sc[b] - h[b]) + atomicAdd(&cur[b], 1);   // LDS atomic: cheap
        srec[pos] = make_int2(src[i] | ((int)f2bf(w[i]) << 16), d & 511);
        sbin[pos] = (unsigned char)b;
    }
    __syncthreads();
    for (int j = t; j < cnt; j += blockDim.x) {
        int b = sbin[j];
        tmp[gbase[b] + (j - (sc[b] - h[b]))] = srec[j];   // coalesced runs per bin
    }
}

__global__ __launch_bounds__(256) void place_kernel(const int* __restrict__ binBase,
                                                    const int2* __restrict__ tmp,
                                                    unsigned int* __restrict__ edges,
                                                    int* __restrict__ rowptr, int n) {
    __shared__ int h[512], sc[512], cur[512];
    int b = blockIdx.x;
    int t = threadIdx.x;
    int base = binBase[b], end = binBase[b + 1];
    for (int i = t; i < 512; i += 256) { h[i] = 0; cur[i] = 0; }
    __syncthreads();
    for (int e = base + t; e < end; e += 256)
        atomicAdd(&h[tmp[e].y], 1);
    __syncthreads();
    for (int i = t; i < 512; i += 256) sc[i] = h[i];
    __syncthreads();
    for (int off = 1; off < 512; off <<= 1) {
        int i0 = t, i1 = t + 256;
        int a0 = (i0 >= off) ? sc[i0 - off] : 0;
        int a1 = (i1 >= off) ? sc[i1 - off] : 0;
        __syncthreads();
        sc[i0] += a0;
        sc[i1] += a1;
        __syncthreads();
    }
    int node0 = b << BINSH;
    for (int i = t; i < 512; i += 256) {
        int node = node0 + i;
        if (node <= n) rowptr[node] = base + sc[i] - h[i];   // exclusive
    }
    if (b == 0 && t == 0) rowptr[0] = 0;
    __syncthreads();
    for (int e = base + t; e < end; e += 256) {
        int2 p = tmp[e];
        int loc = p.y;
        int pos = base + (sc[loc] - h[loc]) + atomicAdd(&cur[loc], 1);
        edges[pos] = (unsigned int)p.x;
    }
}

// ---------------- X -> bf16 conversion ----------------

__global__ void cvt_kernel(const float4* __restrict__ xin, ushort4* __restrict__ xout, int n4) {
    int i = blockIdx.x * blockDim.x + threadIdx.x;
    if (i < n4) {
        float4 v = xin[i];
        ushort4 o;
        o.x = f2bf(v.x); o.y = f2bf(v.y); o.z = f2bf(v.z); o.w = f2bf(v.w);
        xout[i] = o;
    }
}

// ---------------- graph boundaries (batch is sorted) ----------------

__global__ void gbound_kernel(const int* __restrict__ batch, int* __restrict__ gstart, int n) {
    int i = blockIdx.x * blockDim.x + threadIdx.x;
    if (i >= n) return;
    int g = batch[i];
    int gp = (i == 0) ? -1 : batch[i - 1];
    for (int gg = gp + 1; gg <= g; ++gg) gstart[gg] = i;
    if (i == n - 1)
        for (int gg = g + 1; gg <= NUM_GRAPHS; ++gg) gstart[gg] = n;
}

// ---------------- SpMM (pull, no atomics), D=32 bf16, 4B edge recs ----------
// 8 lanes/node; lane owns cols 4l..4l+3 (ushort4). fp32 accum, bf16 store.
//
// In-kernel L2 warming: each block's prologue streams a distinct ~16KB slice
// of x (slice id = blockIdx>>3; the 8 round-robin XCD classes each cover all
// of x). Converts the compulsory per-XCD 3.2MB first-touch from random-64B
// LLC reads (~1.3 TB/s measured) to coalesced streams (~6 TB/s); subsequent
// gathers hit L2. Loads kept alive via x0.0f accumulator (values finite).

__global__ __launch_bounds__(256) void spmm_kernel(const ushort4* __restrict__ xin,
                                                   ushort4* __restrict__ yout,
                                                   const int* __restrict__ rowptr,
                                                   const unsigned int* __restrict__ edges,
                                                   int n) {
    // ---- warm prologue ----
    float d = 0.f;
    {
        const int TOT = N_NODES * 4;            // x as uint4 count (3.2MB/16B)
        int nsl = (int)(gridDim.x + 7) >> 3;    // slices per class
        int slice = (int)blockIdx.x >> 3;
        int per = (TOT + nsl - 1) / nsl;
        int s0 = slice * per, s1 = min(s0 + per, TOT);
        const uint4* __restrict__ xw = (const uint4*)xin;
        for (int i = s0 + (int)threadIdx.x; i < s1; i += 256) {
            uint4 v = xw[i];
            d += __uint_as_float(v.x) * 0.0f + __uint_as_float(v.z) * 0.0f;
        }
    }
    // ---- gather ----
    int lane = threadIdx.x & 7;
    int node = (blockIdx.x * blockDim.x + threadIdx.x) >> 3;
    if (node >= n) return;
    int e0 = rowptr[node], e1 = rowptr[node + 1];
    float a0 = d, a1 = 0.f, a2 = 0.f, a3 = 0.f;
    int e = e0;
    int e8 = e0 + ((e1 - e0) & ~7);
    for (; e < e8; e += 8) {
        unsigned int r[8];
        #pragma unroll
        for (int u = 0; u < 8; ++u) r[u] = edges[e + u];
        ushort4 v[8];
        #pragma unroll
        for (int u = 0; u < 8; ++u)
            v[u] = xin[(size_t)(r[u] & 0xffff) * 8 + lane];
        #pragma unroll
        for (int u = 0; u < 8; ++u) {
            float w = bf2f((unsigned short)(r[u] >> 16));
            a0 += bf2f(v[u].x) * w;
            a1 += bf2f(v[u].y) * w;
            a2 += bf2f(v[u].z) * w;
            a3 += bf2f(v[u].w) * w;
        }
    }
    for (; e < e1; ++e) {
        unsigned int r = edges[e];
        ushort4 v = xin[(size_t)(r & 0xffff) * 8 + lane];
        float w = bf2f((unsigned short)(r >> 16));
        a0 += bf2f(v.x) * w; a1 += bf2f(v.y) * w; a2 += bf2f(v.z) * w; a3 += bf2f(v.w) * w;
    }
    yout[(size_t)node * 8 + lane] = make_ushort4(f2bf(a0), f2bf(a1), f2bf(a2), f2bf(a3));
}

// ---------------- fused pooling: 10 terms, 64 graphs x 16 slices -------------

struct PoolArgs10 {
    const unsigned short* P[10];
    const unsigned short* Q[10];
};

__global__ __launch_bounds__(320) void pool_kernel(PoolArgs10 a, const int* __restrict__ gstart,
                                                   float* __restrict__ out) {
    int k = threadIdx.x >> 5;
    int f = threadIdx.x & 31;
    int g = blockIdx.x >> 4;
    int s = blockIdx.x & 15;
    int gs = gstart[g], ge = gstart[g + 1];
    int len = ge - gs;
    int i0 = gs + ((len * s) >> 4);
    int i1 = gs + ((len * (s + 1)) >> 4);
    const unsigned short* __restrict__ P = a.P[k];
    const unsigned short* __restrict__ Q = a.Q[k];
    float acc = 0.f;
    if (Q) {
        for (int i = i0; i < i1; ++i)
            acc += fabsf(bf2f(P[(size_t)i * 32 + f]) - bf2f(Q[(size_t)i * 32 + f]));
    } else {
        for (int i = i0; i < i1; ++i)
            acc += bf2f(P[(size_t)i * 32 + f]);
    }
    if (i1 > i0) atomicAdd(&out[g * FEATS + k * 32 + f], acc);
}

__global__ void divide_kernel(float* __restrict__ out, const int* __restrict__ gstart, int total) {
    int i = blockIdx.x * blockDim.x + threadIdx.x;
    if (i < total) {
        int g = i / FEATS;
        float c = (float)(gstart[g + 1] - gstart[g]);
        out[i] /= fmaxf(c, 1.0f);
    }
}

// ---------------- host launch ----------------

extern "C" void kernel_launch(void* const* d_in, const int* in_sizes, int n_in,
                              void* d_out, int out_size, void* d_ws, size_t ws_size,
                              hipStream_t stream) {
    const float* X     = (const float*)d_in[0];
    const int*   ei    = (const int*)d_in[1];
    const float* ew    = (const float*)d_in[2];
    const int*   batch = (const int*)d_in[3];
    float* out = (float*)d_out;

    const int N = N_NODES, E = N_EDGES;
    const int* src = ei;
    const int* dst = ei + E;

    char* base = (char*)d_ws;
    size_t off = 0;
    auto alloc = [&](size_t bytes) -> void* {
        void* p = base + off;
        off += (bytes + 255) & ~(size_t)255;
        return p;
    };
    // bf16 diffusion chain buffers y[k] = P^k X, k=0..12 (y[0] = bf16(X))
    unsigned short* y[13];
    for (int k = 0; k <= 12; ++k) y[k] = (unsigned short*)alloc((size_t)N * 32 * 2);

    int*  rowptr  = (int*)alloc((size_t)(N + 4) * 4);
    int*  gstart  = (int*)alloc((NUM_GRAPHS + 1) * 4);
    int*  counts  = (int*)alloc((size_t)NCHUNK * NBIN * 4);
    int*  binBase = (int*)alloc((NBIN + 1) * 4);
    int2* tmp     = (int2*)alloc((size_t)E * 8);
    unsigned int* edges = (unsigned int*)alloc((size_t)E * 4);

    hipMemsetAsync(out, 0, (size_t)out_size * 4, stream);

    // atomic-free CSR build: counts -> positions -> grouped tmp -> edges+rowptr
    binA_kernel<<<NCHUNK, 256, 0, stream>>>(dst, counts, E);
    binB_kernel<<<1, NBIN, 0, stream>>>(counts, binBase);
    binC_kernel<<<NCHUNK, 256, 0, stream>>>(src, dst, ew, counts, tmp, E);
    place_kernel<<<NPB, 256, 0, stream>>>(binBase, tmp, edges, rowptr, N);

    // X -> bf16; graph boundaries
    cvt_kernel<<<(N * 32 / 4 + 255) / 256, 256, 0, stream>>>((const float4*)X, (ushort4*)y[0],
                                                             N * 32 / 4);
    gbound_kernel<<<(N + 255) / 256, 256, 0, stream>>>(batch, gstart, N);

    // ---- single D=32 bf16 diffusion chain: y[k] = P y[k-1], k = 1..12
    const int SPMM_GRID = (N * 8 + 255) / 256;  // 1563 blocks, 32 nodes/block
    for (int k = 1; k <= 12; ++k) {
        spmm_kernel<<<SPMM_GRID, 256, 0, stream>>>((const ushort4*)y[k - 1], (ushort4*)y[k],
                                                   rowptr, edges, N);
    }

    // ---- fused pooling of all 10 feature column-blocks
    // F0 = y8 | F1: |y1-y2|, |y2-y4|, |y4-y8|
    // F2 (ref order): |y3-y2|, |y5-y3|, |y9-y5|, |y6-y4|, |y10-y6|, |y12-y8|
    {
        PoolArgs10 p{};
        const unsigned short* Ps[10] = {y[8], y[1], y[2], y[4], y[3], y[5], y[9], y[6], y[10], y[12]};
        const unsigned short* Qs[10] = {nullptr, y[2], y[4], y[8], y[2], y[3], y[5], y[4], y[6], y[8]};
        for (int k = 0; k < 10; ++k) { p.P[k] = Ps[k]; p.Q[k] = Qs[k]; }
        pool_kernel<<<NUM_GRAPHS * 16, 320, 0, stream>>>(p, gstart, out);
    }

    divide_kernel<<<(out_size + 255) / 256, 256, 0, stream>>>(out, gstart, out_size);
}

// Round 11
// 306.207 us; speedup vs baseline: 1.2804x; 1.1397x over previous
//
#include <hip/hip_runtime.h>

#define N_NODES 50000
#define N_EDGES 800000
#define D_FEAT 32
#define NUM_GRAPHS 64
#define FEATS 320
#define NBIN 128                         // bins of 512 nodes (98 used)
#define BINSH 9
#define CE 4096                          // edges per binning chunk
#define NCHUNK ((N_EDGES + CE - 1) / CE) // 196
#define NPB ((N_NODES + 511) / 512)      // 98 place blocks
#define HALF4 (N_NODES * 4)              // ushort4 per column-half buffer
#define HALFS (N_NODES * 16)             // ushort per column-half buffer

// bf16 helpers (RNE pack, shift unpack) — values finite, no NaN path needed
__device__ __forceinline__ unsigned short f2bf(float f) {
    unsigned int u = __float_as_uint(f);
    u = (u + 0x7fffu + ((u >> 16) & 1u)) >> 16;
    return (unsigned short)u;
}
__device__ __forceinline__ float bf2f(unsigned short h) {
    return __uint_as_float((unsigned int)h << 16);
}

// ---------------- atomic-free binning sort (counts -> positions -> place) ----

__global__ void binA_kernel(const int* __restrict__ dst, int* __restrict__ counts, int n) {
    __shared__ int h[NBIN];
    int t = threadIdx.x;
    if (t < NBIN) h[t] = 0;
    __syncthreads();
    int s0 = blockIdx.x * CE, e0 = min(s0 + CE, n);
    for (int i = s0 + t; i < e0; i += blockDim.x)
        atomicAdd(&h[dst[i] >> BINSH], 1);
    __syncthreads();
    if (t < NBIN) counts[blockIdx.x * NBIN + t] = h[t];
}

__global__ void binB_kernel(int* __restrict__ counts, int* __restrict__ binBase) {
    __shared__ int s[NBIN];
    int b = threadIdx.x;
    int tot = 0;
    #pragma unroll 8
    for (int c = 0; c < NCHUNK; ++c) tot += counts[c * NBIN + b];
    s[b] = tot;
    __syncthreads();
    for (int off = 1; off < NBIN; off <<= 1) {
        int u = (b >= off) ? s[b - off] : 0;
        __syncthreads();
        s[b] += u;
        __syncthreads();
    }
    int base = s[b] - tot;   // exclusive
    binBase[b] = base;
    if (b == NBIN - 1) binBase[NBIN] = s[b];
    int running = base;
    #pragma unroll 4
    for (int c = 0; c < NCHUNK; ++c) {
        int idx = c * NBIN + b;
        int v = counts[idx];
        counts[idx] = running;
        running += v;
    }
}

__global__ __launch_bounds__(256) void binC_kernel(const int* __restrict__ src,
                                                   const int* __restrict__ dst,
                                                   const float* __restrict__ w,
                                                   const int* __restrict__ counts,
                                                   int2* __restrict__ tmp, int n) {
    __shared__ int h[NBIN], sc[NBIN], cur[NBIN], gbase[NBIN];
    __shared__ int2 srec[CE];
    __shared__ unsigned char sbin[CE];
    int t = threadIdx.x;
    if (t < NBIN) h[t] = 0;
    __syncthreads();
    int s0 = blockIdx.x * CE, e0 = min(s0 + CE, n);
    int cnt = e0 - s0;
    for (int i = s0 + t; i < e0; i += blockDim.x)
        atomicAdd(&h[dst[i] >> BINSH], 1);
    __syncthreads();
    if (t < NBIN) sc[t] = h[t];
    __syncthreads();
    for (int off = 1; off < NBIN; off <<= 1) {
        int u = (t < NBIN && t >= off) ? sc[t - off] : 0;
        __syncthreads();
        if (t < NBIN) sc[t] += u;   // inclusive; exclusive = sc[b]-h[b]
        __syncthreads();
    }
    if (t < NBIN) {
        cur[t] = 0;
        gbase[t] = counts[blockIdx.x * NBIN + t];
    }
    __syncthreads();
    for (int i = s0 + t; i < e0; i += blockDim.x) {
        int d = dst[i];
        int b = d >> BINSH;
        int pos = (sc[b] - h[b]) + atomicAdd(&cur[b], 1);   // LDS atomic: cheap
        srec[pos] = make_int2(src[i] | ((int)f2bf(w[i]) << 16), d & 511);
        sbin[pos] = (unsigned char)b;
    }
    __syncthreads();
    for (int j = t; j < cnt; j += blockDim.x) {
        int b = sbin[j];
        tmp[gbase[b] + (j - (sc[b] - h[b]))] = srec[j];   // coalesced runs per bin
    }
}

__global__ __launch_bounds__(256) void place_kernel(const int* __restrict__ binBase,
                                                    const int2* __restrict__ tmp,
                                                    unsigned int* __restrict__ edges,
                                                    int* __restrict__ rowptr, int n) {
    __shared__ int h[512], sc[512], cur[512];
    int b = blockIdx.x;
    int t = threadIdx.x;
    int base = binBase[b], end = binBase[b + 1];
    for (int i = t; i < 512; i += 256) { h[i] = 0; cur[i] = 0; }
    __syncthreads();
    for (int e = base + t; e < end; e += 256)
        atomicAdd(&h[tmp[e].y], 1);
    __syncthreads();
    for (int i = t; i < 512; i += 256) sc[i] = h[i];
    __syncthreads();
    for (int off = 1; off < 512; off <<= 1) {
        int i0 = t, i1 = t + 256;
        int a0 = (i0 >= off) ? sc[i0 - off] : 0;
        int a1 = (i1 >= off) ? sc[i1 - off] : 0;
        __syncthreads();
        sc[i0] += a0;
        sc[i1] += a1;
        __syncthreads();
    }
    int node0 = b << BINSH;
    for (int i = t; i < 512; i += 256) {
        int node = node0 + i;
        if (node <= n) rowptr[node] = base + sc[i] - h[i];   // exclusive
    }
    if (b == 0 && t == 0) rowptr[0] = 0;
    __syncthreads();
    for (int e = base + t; e < end; e += 256) {
        int2 p = tmp[e];
        int loc = p.y;
        int pos = base + (sc[loc] - h[loc]) + atomicAdd(&cur[loc], 1);
        edges[pos] = (unsigned int)p.x;
    }
}

// ---------------- X -> bf16 (column-split layout) ----------------
// Split layout: half h (cols 16h..16h+15) of node i lives at
// ushort offset h*HALFS + i*16 + (col-16h).

__global__ void cvt_kernel(const float4* __restrict__ xin, ushort4* __restrict__ xout, int n) {
    int i = blockIdx.x * blockDim.x + threadIdx.x;   // over N*8 float4 (4 cols each)
    if (i >= n * 8) return;
    int node = i >> 3, q = i & 7;                    // q: which 4-col group
    float4 v = xin[i];
    ushort4 o;
    o.x = f2bf(v.x); o.y = f2bf(v.y); o.z = f2bf(v.z); o.w = f2bf(v.w);
    xout[(size_t)(q >> 2) * HALF4 + (size_t)node * 4 + (q & 3)] = o;
}

// ---------------- graph boundaries (batch is sorted) ----------------

__global__ void gbound_kernel(const int* __restrict__ batch, int* __restrict__ gstart, int n) {
    int i = blockIdx.x * blockDim.x + threadIdx.x;
    if (i >= n) return;
    int g = batch[i];
    int gp = (i == 0) ? -1 : batch[i - 1];
    for (int gg = gp + 1; gg <= g; ++gg) gstart[gg] = i;
    if (i == n - 1)
        for (int gg = g + 1; gg <= NUM_GRAPHS; ++gg) gstart[gg] = n;
}

// ---------------- SpMM, column-split (pull, no atomics) ----------------
// Each block handles ONE 16-col half for 64 nodes; half = (blockIdx&7)>>2.
// With the documented round-robin blockIdx%8 -> XCD mapping, XCDs 0-3 touch
// only half A (1.6 MB), XCDs 4-7 only half B -> unique L2 misses halve
// (200k vs 400k per step; misses retire ~1/cy/XCD = the measured bottleneck).
// Mis-mapping degrades to baseline miss count (no regression mode).
// 4 lanes/node (ushort4 = 4 cols); fp32 accum, bf16 store.

__global__ __launch_bounds__(256) void spmm_kernel(const ushort4* __restrict__ xin,
                                                   ushort4* __restrict__ yout,
                                                   const int* __restrict__ rowptr,
                                                   const unsigned int* __restrict__ edges,
                                                   int n) {
    int c = blockIdx.x & 7;
    int half = c >> 2;
    int sub = ((blockIdx.x >> 3) << 2) + (c & 3);
    int lane = threadIdx.x & 3;
    int node = sub * 64 + (threadIdx.x >> 2);
    if (node >= n) return;
    const ushort4* __restrict__ xh = xin + (size_t)half * HALF4;
    int e0 = rowptr[node], e1 = rowptr[node + 1];
    float a0 = 0.f, a1 = 0.f, a2 = 0.f, a3 = 0.f;
    int e = e0;
    int e8 = e0 + ((e1 - e0) & ~7);
    for (; e < e8; e += 8) {
        unsigned int r[8];
        #pragma unroll
        for (int u = 0; u < 8; ++u) r[u] = edges[e + u];
        ushort4 v[8];
        #pragma unroll
        for (int u = 0; u < 8; ++u)
            v[u] = xh[(size_t)(r[u] & 0xffff) * 4 + lane];
        #pragma unroll
        for (int u = 0; u < 8; ++u) {
            float w = bf2f((unsigned short)(r[u] >> 16));
            a0 += bf2f(v[u].x) * w;
            a1 += bf2f(v[u].y) * w;
            a2 += bf2f(v[u].z) * w;
            a3 += bf2f(v[u].w) * w;
        }
    }
    for (; e < e1; ++e) {
        unsigned int r = edges[e];
        ushort4 v = xh[(size_t)(r & 0xffff) * 4 + lane];
        float w = bf2f((unsigned short)(r >> 16));
        a0 += bf2f(v.x) * w; a1 += bf2f(v.y) * w; a2 += bf2f(v.z) * w; a3 += bf2f(v.w) * w;
    }
    yout[(size_t)half * HALF4 + (size_t)node * 4 + lane] =
        make_ushort4(f2bf(a0), f2bf(a1), f2bf(a2), f2bf(a3));
}

// ---------------- fused pooling: 10 terms, 64 graphs x 16 slices -------------
// P/Q are split-layout buffers: elem (i,f) at (f>>4)*HALFS + i*16 + (f&15).

struct PoolArgs10 {
    const unsigned short* P[10];
    const unsigned short* Q[10];
};

__global__ __launch_bounds__(320) void pool_kernel(PoolArgs10 a, const int* __restrict__ gstart,
                                                   float* __restrict__ out) {
    int k = threadIdx.x >> 5;
    int f = threadIdx.x & 31;
    int g = blockIdx.x >> 4;
    int s = blockIdx.x & 15;
    int gs = gstart[g], ge = gstart[g + 1];
    int len = ge - gs;
    int i0 = gs + ((len * s) >> 4);
    int i1 = gs + ((len * (s + 1)) >> 4);
    size_t off = (size_t)(f >> 4) * HALFS + (f & 15);
    const unsigned short* __restrict__ P = a.P[k] + off;
    const unsigned short* __restrict__ Q = a.Q[k] ? (a.Q[k] + off) : nullptr;
    float acc = 0.f;
    if (Q) {
        for (int i = i0; i < i1; ++i)
            acc += fabsf(bf2f(P[(size_t)i * 16]) - bf2f(Q[(size_t)i * 16]));
    } else {
        for (int i = i0; i < i1; ++i)
            acc += bf2f(P[(size_t)i * 16]);
    }
    if (i1 > i0) atomicAdd(&out[g * FEATS + k * 32 + f], acc);
}

__global__ void divide_kernel(float* __restrict__ out, const int* __restrict__ gstart, int total) {
    int i = blockIdx.x * blockDim.x + threadIdx.x;
    if (i < total) {
        int g = i / FEATS;
        float c = (float)(gstart[g + 1] - gstart[g]);
        out[i] /= fmaxf(c, 1.0f);
    }
}

// ---------------- host launch ----------------

extern "C" void kernel_launch(void* const* d_in, const int* in_sizes, int n_in,
                              void* d_out, int out_size, void* d_ws, size_t ws_size,
                              hipStream_t stream) {
    const float* X     = (const float*)d_in[0];
    const int*   ei    = (const int*)d_in[1];
    const float* ew    = (const float*)d_in[2];
    const int*   batch = (const int*)d_in[3];
    float* out = (float*)d_out;

    const int N = N_NODES, E = N_EDGES;
    const int* src = ei;
    const int* dst = ei + E;

    char* base = (char*)d_ws;
    size_t off = 0;
    auto alloc = [&](size_t bytes) -> void* {
        void* p = base + off;
        off += (bytes + 255) & ~(size_t)255;
        return p;
    };
    // bf16 diffusion chain buffers (column-split layout), y[k] = P^k X
    unsigned short* y[13];
    for (int k = 0; k <= 12; ++k) y[k] = (unsigned short*)alloc((size_t)N * 32 * 2);

    int*  rowptr  = (int*)alloc((size_t)(N + 4) * 4);
    int*  gstart  = (int*)alloc((NUM_GRAPHS + 1) * 4);
    int*  counts  = (int*)alloc((size_t)NCHUNK * NBIN * 4);
    int*  binBase = (int*)alloc((NBIN + 1) * 4);
    int2* tmp     = (int2*)alloc((size_t)E * 8);
    unsigned int* edges = (unsigned int*)alloc((size_t)E * 4);

    hipMemsetAsync(out, 0, (size_t)out_size * 4, stream);

    // atomic-free CSR build: counts -> positions -> grouped tmp -> edges+rowptr
    binA_kernel<<<NCHUNK, 256, 0, stream>>>(dst, counts, E);
    binB_kernel<<<1, NBIN, 0, stream>>>(counts, binBase);
    binC_kernel<<<NCHUNK, 256, 0, stream>>>(src, dst, ew, counts, tmp, E);
    place_kernel<<<NPB, 256, 0, stream>>>(binBase, tmp, edges, rowptr, N);

    // X -> bf16 split layout; graph boundaries
    cvt_kernel<<<(N * 8 + 255) / 256, 256, 0, stream>>>((const float4*)X, (ushort4*)y[0], N);
    gbound_kernel<<<(N + 255) / 256, 256, 0, stream>>>(batch, gstart, N);

    // ---- single D=32 bf16 diffusion chain: y[k] = P y[k-1], k = 1..12
    // grid: 196 groups x 8 classes; classes 0-3 -> half A, 4-7 -> half B
    const int SPMM_GRID = 196 * 8;
    for (int k = 1; k <= 12; ++k) {
        spmm_kernel<<<SPMM_GRID, 256, 0, stream>>>((const ushort4*)y[k - 1], (ushort4*)y[k],
                                                   rowptr, edges, N);
    }

    // ---- fused pooling of all 10 feature column-blocks
    // F0 = y8 | F1: |y1-y2|, |y2-y4|, |y4-y8|
    // F2 (ref order): |y3-y2|, |y5-y3|, |y9-y5|, |y6-y4|, |y10-y6|, |y12-y8|
    {
        PoolArgs10 p{};
        const unsigned short* Ps[10] = {y[8], y[1], y[2], y[4], y[3], y[5], y[9], y[6], y[10], y[12]};
        const unsigned short* Qs[10] = {nullptr, y[2], y[4], y[8], y[2], y[3], y[5], y[4], y[6], y[8]};
        for (int k = 0; k < 10; ++k) { p.P[k] = Ps[k]; p.Q[k] = Qs[k]; }
        pool_kernel<<<NUM_GRAPHS * 16, 320, 0, stream>>>(p, gstart, out);
    }

    divide_kernel<<<(out_size + 255) / 256, 256, 0, stream>>>(out, gstart, out_size);
}

// Round 12
// 291.785 us; speedup vs baseline: 1.3437x; 1.0494x over previous
//
#include <hip/hip_runtime.h>

#define N_NODES 50000
#define N_EDGES 800000
#define D_FEAT 32
#define NUM_GRAPHS 64
#define FEATS 320
#define NBIN 128                         // bins of 512 nodes (98 used)
#define BINSH 9
#define CE 4096                          // edges per binning chunk
#define NCHUNK ((N_EDGES + CE - 1) / CE) // 196
#define NPB ((N_NODES + 511) / 512)      // 98 place blocks

// bf16 helpers (RNE pack, shift unpack) — values finite, no NaN path needed
__device__ __forceinline__ unsigned short f2bf(float f) {
    unsigned int u = __float_as_uint(f);
    u = (u + 0x7fffu + ((u >> 16) & 1u)) >> 16;
    return (unsigned short)u;
}
__device__ __forceinline__ float bf2f(unsigned short h) {
    return __uint_as_float((unsigned int)h << 16);
}

// ---------------- atomic-free binning sort (counts -> positions -> place) ----

__global__ void binA_kernel(const int* __restrict__ dst, int* __restrict__ counts, int n) {
    __shared__ int h[NBIN];
    int t = threadIdx.x;
    if (t < NBIN) h[t] = 0;
    __syncthreads();
    int s0 = blockIdx.x * CE, e0 = min(s0 + CE, n);
    for (int i = s0 + t; i < e0; i += blockDim.x)
        atomicAdd(&h[dst[i] >> BINSH], 1);
    __syncthreads();
    if (t < NBIN) counts[blockIdx.x * NBIN + t] = h[t];
}

__global__ void binB_kernel(int* __restrict__ counts, int* __restrict__ binBase) {
    __shared__ int s[NBIN];
    int b = threadIdx.x;
    int tot = 0;
    #pragma unroll 8
    for (int c = 0; c < NCHUNK; ++c) tot += counts[c * NBIN + b];
    s[b] = tot;
    __syncthreads();
    for (int off = 1; off < NBIN; off <<= 1) {
        int u = (b >= off) ? s[b - off] : 0;
        __syncthreads();
        s[b] += u;
        __syncthreads();
    }
    int base = s[b] - tot;   // exclusive
    binBase[b] = base;
    if (b == NBIN - 1) binBase[NBIN] = s[b];
    int running = base;
    #pragma unroll 4
    for (int c = 0; c < NCHUNK; ++c) {
        int idx = c * NBIN + b;
        int v = counts[idx];
        counts[idx] = running;
        running += v;
    }
}

__global__ __launch_bounds__(256) void binC_kernel(const int* __restrict__ src,
                                                   const int* __restrict__ dst,
                                                   const float* __restrict__ w,
                                                   const int* __restrict__ counts,
                                                   int2* __restrict__ tmp, int n) {
    __shared__ int h[NBIN], sc[NBIN], cur[NBIN], gbase[NBIN];
    __shared__ int2 srec[CE];
    __shared__ unsigned char sbin[CE];
    int t = threadIdx.x;
    if (t < NBIN) h[t] = 0;
    __syncthreads();
    int s0 = blockIdx.x * CE, e0 = min(s0 + CE, n);
    int cnt = e0 - s0;
    for (int i = s0 + t; i < e0; i += blockDim.x)
        atomicAdd(&h[dst[i] >> BINSH], 1);
    __syncthreads();
    if (t < NBIN) sc[t] = h[t];
    __syncthreads();
    for (int off = 1; off < NBIN; off <<= 1) {
        int u = (t < NBIN && t >= off) ? sc[t - off] : 0;
        __syncthreads();
        if (t < NBIN) sc[t] += u;   // inclusive; exclusive = sc[b]-h[b]
        __syncthreads();
    }
    if (t < NBIN) {
        cur[t] = 0;
        gbase[t] = counts[blockIdx.x * NBIN + t];
    }
    __syncthreads();
    for (int i = s0 + t; i < e0; i += blockDim.x) {
        int d = dst[i];
        int b = d >> BINSH;
        int pos = (sc[b] - h[b]) + atomicAdd(&cur[b], 1);   // LDS atomic: cheap
        srec[pos] = make_int2(src[i] | ((int)f2bf(w[i]) << 16), d & 511);
        sbin[pos] = (unsigned char)b;
    }
    __syncthreads();
    for (int j = t; j < cnt; j += blockDim.x) {
        int b = sbin[j];
        tmp[gbase[b] + (j - (sc[b] - h[b]))] = srec[j];   // coalesced runs per bin
    }
}

__global__ __launch_bounds__(256) void place_kernel(const int* __restrict__ binBase,
                                                    const int2* __restrict__ tmp,
                                                    unsigned int* __restrict__ edges,
                                                    int* __restrict__ rowptr, int n) {
    __shared__ int h[512], sc[512], cur[512];
    int b = blockIdx.x;
    int t = threadIdx.x;
    int base = binBase[b], end = binBase[b + 1];
    for (int i = t; i < 512; i += 256) { h[i] = 0; cur[i] = 0; }
    __syncthreads();
    for (int e = base + t; e < end; e += 256)
        atomicAdd(&h[tmp[e].y], 1);
    __syncthreads();
    for (int i = t; i < 512; i += 256) sc[i] = h[i];
    __syncthreads();
    for (int off = 1; off < 512; off <<= 1) {
        int i0 = t, i1 = t + 256;
        int a0 = (i0 >= off) ? sc[i0 - off] : 0;
        int a1 = (i1 >= off) ? sc[i1 - off] : 0;
        __syncthreads();
        sc[i0] += a0;
        sc[i1] += a1;
        __syncthreads();
    }
    int node0 = b << BINSH;
    for (int i = t; i < 512; i += 256) {
        int node = node0 + i;
        if (node <= n) rowptr[node] = base + sc[i] - h[i];   // exclusive
    }
    if (b == 0 && t == 0) rowptr[0] = 0;
    __syncthreads();
    for (int e = base + t; e < end; e += 256) {
        int2 p = tmp[e];
        int loc = p.y;
        int pos = base + (sc[loc] - h[loc]) + atomicAdd(&cur[loc], 1);
        edges[pos] = (unsigned int)p.x;
    }
}

// ---------------- prep: X -> bf16 conversion + graph boundaries -------------

__global__ void prep_kernel(const float4* __restrict__ xin, ushort4* __restrict__ xout,
                            const int* __restrict__ batch, int* __restrict__ gstart, int n) {
    int i = blockIdx.x * blockDim.x + threadIdx.x;
    if (i < n * 8) {
        float4 v = xin[i];
        ushort4 o;
        o.x = f2bf(v.x); o.y = f2bf(v.y); o.z = f2bf(v.z); o.w = f2bf(v.w);
        xout[i] = o;
    }
    if (i < n) {
        int g = batch[i];
        int gp = (i == 0) ? -1 : batch[i - 1];
        for (int gg = gp + 1; gg <= g; ++gg) gstart[gg] = i;
        if (i == n - 1)
            for (int gg = g + 1; gg <= NUM_GRAPHS; ++gg) gstart[gg] = n;
    }
}

// ---------------- SpMM (pull, no atomics), D=32 bf16, 4B edge recs ----------
// 8 lanes/node; lane owns cols 4l..4l+3 (ushort4). unroll 8. fp32 accum.
// Structural floor (measured r8-r11): 8 XCDs x 3.2MB/64B = 400k compulsory L2
// misses/step @ ~1/cy/XCD => ~20us/step. XCD choreography (copy/warm/split)
// failed 3x — placement not exploitable from HIP.

__global__ __launch_bounds__(256) void spmm_kernel(const ushort4* __restrict__ xin,
                                                   ushort4* __restrict__ yout,
                                                   const int* __restrict__ rowptr,
                                                   const unsigned int* __restrict__ edges,
                                                   int n) {
    int lane = threadIdx.x & 7;
    int node = (blockIdx.x * blockDim.x + threadIdx.x) >> 3;
    if (node >= n) return;
    int e0 = rowptr[node], e1 = rowptr[node + 1];
    float a0 = 0.f, a1 = 0.f, a2 = 0.f, a3 = 0.f;
    int e = e0;
    int e8 = e0 + ((e1 - e0) & ~7);
    for (; e < e8; e += 8) {
        unsigned int r[8];
        #pragma unroll
        for (int u = 0; u < 8; ++u) r[u] = edges[e + u];
        ushort4 v[8];
        #pragma unroll
        for (int u = 0; u < 8; ++u)
            v[u] = xin[(size_t)(r[u] & 0xffff) * 8 + lane];
        #pragma unroll
        for (int u = 0; u < 8; ++u) {
            float w = bf2f((unsigned short)(r[u] >> 16));
            a0 += bf2f(v[u].x) * w;
            a1 += bf2f(v[u].y) * w;
            a2 += bf2f(v[u].z) * w;
            a3 += bf2f(v[u].w) * w;
        }
    }
    for (; e < e1; ++e) {
        unsigned int r = edges[e];
        ushort4 v = xin[(size_t)(r & 0xffff) * 8 + lane];
        float w = bf2f((unsigned short)(r >> 16));
        a0 += bf2f(v.x) * w; a1 += bf2f(v.y) * w; a2 += bf2f(v.z) * w; a3 += bf2f(v.w) * w;
    }
    yout[(size_t)node * 8 + lane] = make_ushort4(f2bf(a0), f2bf(a1), f2bf(a2), f2bf(a3));
}

// ---------------- fused pooling: 10 terms, 64 graphs x 16 slices -------------
// Mean fused in: each slice contributes acc/len (len from gstart, no divide
// kernel). term k covers out cols [32k,32k+32); Q==nullptr -> raw P else |P-Q|.

struct PoolArgs10 {
    const unsigned short* P[10];
    const unsigned short* Q[10];
};

__global__ __launch_bounds__(320) void pool_kernel(PoolArgs10 a, const int* __restrict__ gstart,
                                                   float* __restrict__ out) {
    int k = threadIdx.x >> 5;
    int f = threadIdx.x & 31;
    int g = blockIdx.x >> 4;
    int s = blockIdx.x & 15;
    int gs = gstart[g], ge = gstart[g + 1];
    int len = ge - gs;
    int i0 = gs + ((len * s) >> 4);
    int i1 = gs + ((len * (s + 1)) >> 4);
    const unsigned short* __restrict__ P = a.P[k];
    const unsigned short* __restrict__ Q = a.Q[k];
    float acc = 0.f;
    if (Q) {
        for (int i = i0; i < i1; ++i)
            acc += fabsf(bf2f(P[(size_t)i * 32 + f]) - bf2f(Q[(size_t)i * 32 + f]));
    } else {
        for (int i = i0; i < i1; ++i)
            acc += bf2f(P[(size_t)i * 32 + f]);
    }
    if (i1 > i0) {
        float inv = 1.0f / (float)max(len, 1);
        atomicAdd(&out[g * FEATS + k * 32 + f], acc * inv);
    }
}

// ---------------- host launch ----------------

extern "C" void kernel_launch(void* const* d_in, const int* in_sizes, int n_in,
                              void* d_out, int out_size, void* d_ws, size_t ws_size,
                              hipStream_t stream) {
    const float* X     = (const float*)d_in[0];
    const int*   ei    = (const int*)d_in[1];
    const float* ew    = (const float*)d_in[2];
    const int*   batch = (const int*)d_in[3];
    float* out = (float*)d_out;

    const int N = N_NODES, E = N_EDGES;
    const int* src = ei;
    const int* dst = ei + E;

    char* base = (char*)d_ws;
    size_t off = 0;
    auto alloc = [&](size_t bytes) -> void* {
        void* p = base + off;
        off += (bytes + 255) & ~(size_t)255;
        return p;
    };
    // bf16 diffusion chain buffers y[k] = P^k X, k=0..12 (y[0] = bf16(X))
    unsigned short* y[13];
    for (int k = 0; k <= 12; ++k) y[k] = (unsigned short*)alloc((size_t)N * 32 * 2);

    int*  rowptr  = (int*)alloc((size_t)(N + 4) * 4);
    int*  gstart  = (int*)alloc((NUM_GRAPHS + 1) * 4);
    int*  counts  = (int*)alloc((size_t)NCHUNK * NBIN * 4);
    int*  binBase = (int*)alloc((NBIN + 1) * 4);
    int2* tmp     = (int2*)alloc((size_t)E * 8);
    unsigned int* edges = (unsigned int*)alloc((size_t)E * 4);

    hipMemsetAsync(out, 0, (size_t)out_size * 4, stream);

    // atomic-free CSR build: counts -> positions -> grouped tmp -> edges+rowptr
    binA_kernel<<<NCHUNK, 256, 0, stream>>>(dst, counts, E);
    binB_kernel<<<1, NBIN, 0, stream>>>(counts, binBase);
    binC_kernel<<<NCHUNK, 256, 0, stream>>>(src, dst, ew, counts, tmp, E);
    place_kernel<<<NPB, 256, 0, stream>>>(binBase, tmp, edges, rowptr, N);

    // X -> bf16 + graph boundaries (merged)
    prep_kernel<<<(N * 8 + 255) / 256, 256, 0, stream>>>((const float4*)X, (ushort4*)y[0],
                                                         batch, gstart, N);

    // ---- single D=32 bf16 diffusion chain: y[k] = P y[k-1], k = 1..12
    const int SPMM_GRID = (N * 8 + 255) / 256;  // 1563 blocks, 32 nodes/block
    for (int k = 1; k <= 12; ++k) {
        spmm_kernel<<<SPMM_GRID, 256, 0, stream>>>((const ushort4*)y[k - 1], (ushort4*)y[k],
                                                   rowptr, edges, N);
    }

    // ---- fused pooling (mean included) of all 10 feature column-blocks
    // F0 = y8 | F1: |y1-y2|, |y2-y4|, |y4-y8|
    // F2 (ref order): |y3-y2|, |y5-y3|, |y9-y5|, |y6-y4|, |y10-y6|, |y12-y8|
    {
        PoolArgs10 p{};
        const unsigned short* Ps[10] = {y[8], y[1], y[2], y[4], y[3], y[5], y[9], y[6], y[10], y[12]};
        const unsigned short* Qs[10] = {nullptr, y[2], y[4], y[8], y[2], y[3], y[5], y[4], y[6], y[8]};
        for (int k = 0; k < 10; ++k) { p.P[k] = Ps[k]; p.Q[k] = Qs[k]; }
        pool_kernel<<<NUM_GRAPHS * 16, 320, 0, stream>>>(p, gstart, out);
    }
}